// Round 9
// baseline (281.355 us; speedup 1.0000x reference)
//
#include <hip/hip_runtime.h>
#include <hip/hip_cooperative_groups.h>
#include <math.h>

namespace cg = cooperative_groups;

#define BB 8192
#define DD 2048
#define BN_EPS 1e-5f

// ---------------- cooperative fused path ----------------
#define NBLK 512
#define NTHR 512
#define RPB  16   // rows per block   (NBLK * RPB == BB)
#define CPT  4    // cols per thread  (NTHR * CPT == DD)
#define NWV  (NTHR / 64)

// Empirical launch_bounds ledger (gfx950, 512-thr kernel family):
//   (512,4) -> 64-VGPR cap;  (512,1) -> 128-VGPR cap (observed r7,r8);
//   bare    -> heuristic picks 128 AND spills big tiles (r8), or >128 (r6).
// So: keep per-thread state at 64 floats (v[16][4]) and pin (512,1) ->
// ~110 regs used, no spill, 2 blocks/CU -> all 512 blocks co-resident.
// kernel_launch verifies >=2 blocks/CU via occupancy query (ROCm coop
// launch does NOT validate co-residency; oversubscription deadlocks).
__global__ __launch_bounds__(NTHR, 1) void k_fused(
    const float* __restrict__ x, const float* __restrict__ w4,
    const float* __restrict__ b4, float* __restrict__ out,
    float* __restrict__ ws)
{
    cg::grid_group grid = cg::this_grid();
    const int t    = threadIdx.x;
    const int blk  = blockIdx.x;
    const int lane = t & 63;
    const int wv   = t >> 6;
    const int row0 = blk * RPB;
    const int c0   = t * CPT;

    float* partials = ws;                          // [NBLK][2][DD]  (8 MB)
    float* mu_g     = ws + (size_t)NBLK * 2 * DD;  // [DD]
    float* inv_g    = mu_g + DD;                   // [DD]

    __shared__ float lds_red[NWV][RPB];   // 8 x 16
    __shared__ float lds_s[RPB];          // 16
    __shared__ float lds_st[NWV][2 * CPT];

    // v holds the (normalized) running `out`; starts as x.
    float v[RPB][CPT];
    {
        const float* xp = x + (size_t)row0 * DD + c0;
        #pragma unroll
        for (int r = 0; r < RPB; ++r) {
            *(float4*)&v[r][0] = *(const float4*)xp;
            xp += DD;
        }
    }

    for (int l = 0; l < 4; ++l) {
        // ---- row dot: s[row] = sum_d v[row,d] * w[l,d]  (block-local)
        // chunked 8 rows at a time to bound peak register pressure
        {
            float wr[CPT];
            *(float4*)&wr[0] = *(const float4*)(w4 + l * DD + c0);
            #pragma unroll
            for (int ch = 0; ch < RPB / 8; ++ch) {
                float p[8];
                #pragma unroll
                for (int i = 0; i < 8; ++i) {
                    const int r = ch * 8 + i;
                    float a = v[r][0] * wr[0];
                    a = fmaf(v[r][1], wr[1], a);
                    a = fmaf(v[r][2], wr[2], a);
                    a = fmaf(v[r][3], wr[3], a);
                    p[i] = a;
                }
                #pragma unroll
                for (int off = 32; off; off >>= 1) {
                    #pragma unroll
                    for (int i = 0; i < 8; ++i)
                        p[i] += __shfl_xor(p[i], off, 64);
                }
                if (lane == 0) {
                    #pragma unroll
                    for (int i = 0; i < 8; ++i) lds_red[wv][ch * 8 + i] = p[i];
                }
            }
        }
        __syncthreads();
        if (t < RPB) {
            float a = 0.f;
            #pragma unroll
            for (int w = 0; w < NWV; ++w) a += lds_red[w][t];
            lds_s[t] = a;
        }
        __syncthreads();

        // ---- update: v = x*s + bias + v  (running pointer, short live ranges)
        {
            float bv[CPT];
            *(float4*)&bv[0] = *(const float4*)(b4 + l * DD + c0);
            const float* xp = x + (size_t)row0 * DD + c0;
            #pragma unroll
            for (int r = 0; r < RPB; ++r) {
                const float4 x4 = *(const float4*)xp;
                xp += DD;
                const float sv = lds_s[r];
                v[r][0] = fmaf(x4.x, sv, bv[0] + v[r][0]);
                v[r][1] = fmaf(x4.y, sv, bv[1] + v[r][1]);
                v[r][2] = fmaf(x4.z, sv, bv[2] + v[r][2]);
                v[r][3] = fmaf(x4.w, sv, bv[3] + v[r][3]);
            }
        }

        // ---- column partials (register-only post-pass over v)
        {
            float cs[CPT], cq[CPT];
            #pragma unroll
            for (int j = 0; j < CPT; ++j) { cs[j] = 0.f; cq[j] = 0.f; }
            #pragma unroll
            for (int r = 0; r < RPB; ++r) {
                #pragma unroll
                for (int j = 0; j < CPT; ++j) {
                    cs[j] += v[r][j];
                    cq[j]  = fmaf(v[r][j], v[r][j], cq[j]);
                }
            }
            float* pp = partials + (size_t)blk * 2 * DD;
            *(float4*)(pp + c0)      = *(float4*)&cs[0];
            *(float4*)(pp + DD + c0) = *(float4*)&cq[0];
        }

        grid.sync();

        // ---- stats reduce: block b owns cols [4b,4b+4); thread t reads partial t
        {
            const int cb = blk * CPT;
            const float* pb = partials + (size_t)t * 2 * DD;
            float a[CPT], q[CPT];
            *(float4*)&a[0] = *(const float4*)(pb + cb);
            *(float4*)&q[0] = *(const float4*)(pb + DD + cb);
            #pragma unroll
            for (int off = 32; off; off >>= 1) {
                #pragma unroll
                for (int j = 0; j < CPT; ++j) {
                    a[j] += __shfl_xor(a[j], off, 64);
                    q[j] += __shfl_xor(q[j], off, 64);
                }
            }
            if (lane == 0) {
                #pragma unroll
                for (int j = 0; j < CPT; ++j) {
                    lds_st[wv][j]       = a[j];
                    lds_st[wv][CPT + j] = q[j];
                }
            }
            __syncthreads();
            if (t == 0) {
                #pragma unroll
                for (int j = 0; j < CPT; ++j) {
                    float A = 0.f, Q = 0.f;
                    #pragma unroll
                    for (int w = 0; w < NWV; ++w) {
                        A += lds_st[w][j];
                        Q += lds_st[w][CPT + j];
                    }
                    const float m  = A / (float)BB;
                    const float va = fmaxf(Q / (float)BB - m * m, 0.f);
                    mu_g[cb + j]  = m;
                    inv_g[cb + j] = rsqrtf(va + BN_EPS);
                }
            }
        }

        grid.sync();

        // ---- normalize registers
        {
            float mv[CPT], iv[CPT];
            *(float4*)&mv[0] = *(const float4*)(mu_g + c0);
            *(float4*)&iv[0] = *(const float4*)(inv_g + c0);
            #pragma unroll
            for (int r = 0; r < RPB; ++r) {
                #pragma unroll
                for (int j = 0; j < CPT; ++j)
                    v[r][j] = (v[r][j] - mv[j]) * iv[j];
            }
        }
    }

    // ---- final store
    {
        float* op = out + (size_t)row0 * DD + c0;
        #pragma unroll
        for (int r = 0; r < RPB; ++r) {
            *(float4*)op = *(float4*)&v[r][0];
            op += DD;
        }
    }
}

// ---------------- fallback: merged per-layer kernel (dot + update + partials) ----
__global__ __launch_bounds__(512) void k_layer(
    const float* __restrict__ x, const float* __restrict__ raw,
    const float* __restrict__ w, const float* __restrict__ bias,
    const float* __restrict__ mu, const float* __restrict__ inv,
    float* __restrict__ outbuf, float* __restrict__ partials, int use_norm)
{
    const int t    = threadIdx.x;
    const int lane = t & 63;
    const int wv   = t >> 6;
    const int blk  = blockIdx.x;
    const int row0 = blk * 32;

    __shared__ float lds_s[32];

    for (int rw = 0; rw < 4; ++rw) {
        const int row = row0 + wv * 4 + rw;
        const float* rp = raw + (size_t)row * DD;
        float acc = 0.f;
        #pragma unroll
        for (int k = 0; k < DD / 256; ++k) {
            const int idx = k * 256 + lane * 4;
            float4 rv  = *(const float4*)(rp + idx);
            const float4 wv4 = *(const float4*)(w + idx);
            if (use_norm) {
                const float4 m  = *(const float4*)(mu + idx);
                const float4 iv = *(const float4*)(inv + idx);
                rv.x = (rv.x - m.x) * iv.x;
                rv.y = (rv.y - m.y) * iv.y;
                rv.z = (rv.z - m.z) * iv.z;
                rv.w = (rv.w - m.w) * iv.w;
            }
            acc += rv.x * wv4.x + rv.y * wv4.y + rv.z * wv4.z + rv.w * wv4.w;
        }
        #pragma unroll
        for (int off = 32; off; off >>= 1) acc += __shfl_xor(acc, off, 64);
        if (lane == 0) lds_s[wv * 4 + rw] = acc;
    }
    __syncthreads();

    const int c0 = t * 4;
    float4 bv = *(const float4*)(bias + c0);
    float4 m4, iv4;
    if (use_norm) {
        m4  = *(const float4*)(mu + c0);
        iv4 = *(const float4*)(inv + c0);
    } else {
        m4  = make_float4(0.f, 0.f, 0.f, 0.f);
        iv4 = make_float4(1.f, 1.f, 1.f, 1.f);
    }
    float cs[4] = {0.f, 0.f, 0.f, 0.f};
    float cq[4] = {0.f, 0.f, 0.f, 0.f};
    const float* rp = raw + (size_t)row0 * DD + c0;
    const float* xp = x   + (size_t)row0 * DD + c0;
    float*       op = outbuf + (size_t)row0 * DD + c0;
    for (int r = 0; r < 32; ++r) {
        const float4 rv = *(const float4*)rp;
        const float4 x4 = *(const float4*)xp;
        const float  sv = lds_s[r];
        float4 o;
        o.x = fmaf(x4.x, sv, bv.x + (rv.x - m4.x) * iv4.x);
        o.y = fmaf(x4.y, sv, bv.y + (rv.y - m4.y) * iv4.y);
        o.z = fmaf(x4.z, sv, bv.z + (rv.z - m4.z) * iv4.z);
        o.w = fmaf(x4.w, sv, bv.w + (rv.w - m4.w) * iv4.w);
        cs[0] += o.x; cq[0] = fmaf(o.x, o.x, cq[0]);
        cs[1] += o.y; cq[1] = fmaf(o.y, o.y, cq[1]);
        cs[2] += o.z; cq[2] = fmaf(o.z, o.z, cq[2]);
        cs[3] += o.w; cq[3] = fmaf(o.w, o.w, cq[3]);
        *(float4*)op = o;
        rp += DD; xp += DD; op += DD;
    }
    float* pp = partials + (size_t)blk * 2 * DD;
    *(float4*)(pp + c0)      = *(float4*)&cs[0];
    *(float4*)(pp + DD + c0) = *(float4*)&cq[0];
}

__global__ __launch_bounds__(256) void k_stats(
    const float* __restrict__ partials, float* __restrict__ mu, float* __restrict__ inv)
{
    const int col = blockIdx.x * 256 + threadIdx.x;  // grid = DD/256 = 8
    float sum = 0.f, sq = 0.f;
    for (int p = 0; p < 256; ++p) {
        sum += partials[(size_t)p * 2 * DD + col];
        sq  += partials[(size_t)p * 2 * DD + DD + col];
    }
    const float m = sum / (float)BB;
    const float var = fmaxf(sq / (float)BB - m * m, 0.f);
    mu[col]  = m;
    inv[col] = rsqrtf(var + BN_EPS);
}

__global__ __launch_bounds__(256) void k_norm(
    float* __restrict__ out, const float* __restrict__ mu, const float* __restrict__ inv)
{
    const size_t i = ((size_t)blockIdx.x * 256 + threadIdx.x) * 4;
    const int c = (int)(i & (DD - 1));
    float4 v = *(float4*)(out + i);
    const float4 m  = *(const float4*)(mu + c);
    const float4 iv = *(const float4*)(inv + c);
    v.x = (v.x - m.x) * iv.x;
    v.y = (v.y - m.y) * iv.y;
    v.z = (v.z - m.z) * iv.z;
    v.w = (v.w - m.w) * iv.w;
    *(float4*)(out + i) = v;
}

extern "C" void kernel_launch(void* const* d_in, const int* in_sizes, int n_in,
                              void* d_out, int out_size, void* d_ws, size_t ws_size,
                              hipStream_t stream) {
    const float* x  = (const float*)d_in[0];   // [B, D]
    const float* w  = (const float*)d_in[1];   // [4, D]
    const float* bb = (const float*)d_in[2];   // [4, D]
    float* out = (float*)d_out;
    float* ws  = (float*)d_ws;

    // ---- coop path, only if provably co-resident (need 2 blocks/CU for 512 blocks)
    bool coop_ok = false;
    const size_t coop_need = ((size_t)NBLK * 2 * DD + 2 * DD) * sizeof(float);
    if (ws_size >= coop_need) {
        int blocks_per_cu = 0;
        hipError_t qe = hipOccupancyMaxActiveBlocksPerMultiprocessor(
            &blocks_per_cu, (const void*)k_fused, NTHR, 0);
        if (qe == hipSuccess && blocks_per_cu >= 2) {   // 512 blocks / 256 CUs
            void* args[] = { (void*)&x, (void*)&w, (void*)&bb, (void*)&out, (void*)&ws };
            hipError_t e = hipLaunchCooperativeKernel((const void*)k_fused, dim3(NBLK),
                                                      dim3(NTHR), args, 0, stream);
            coop_ok = (e == hipSuccess);
        }
    }
    if (coop_ok) return;

    // ---- fallback: merged per-layer path (9 dispatches)
    float* mu_buf   = ws;
    float* inv_buf  = mu_buf + DD;
    float* partials = inv_buf + DD;   // [256][2][DD] = 4 MB

    for (int l = 0; l < 4; ++l) {
        const float* raw = (l == 0) ? x : out;
        k_layer<<<256, 512, 0, stream>>>(x, raw, w + l * DD, bb + l * DD,
                                         mu_buf, inv_buf, out, partials, l != 0);
        k_stats<<<DD / 256, 256, 0, stream>>>(partials, mu_buf, inv_buf);
    }
    k_norm<<<(BB * DD / 4) / 256, 256, 0, stream>>>(out, mu_buf, inv_buf);
}